// Round 4
// baseline (1586.535 us; speedup 1.0000x reference)
//
#include <hip/hip_runtime.h>
#include <math.h>

// ---------------------------------------------------------------------------
// PINN beam loss via forward-mode bivariate jets (v4: ILP-pipelined).
// Jet of f(z + t*(1,1) + s*(1,0)):  y[k]=coeff t^k, z[k]=coeff t^k s.
// Layer-1: pre-act = p0 + d*t + wx*s  =>  z[k] = (k+1)*(wx/d)*y[k+1] exactly.
// LDS layout per sample (SoA float4 segments, all 16B aligned):
//   seg0[k] = (y0, z0, y1, z1)   seg1[k] = (y2, z2, y3, z3)   seg2[k] = (y4, 0)
// Layer-2/3 inner loops use explicit k+1 register prefetch so ds_read latency
// hides under the current iteration's FMA block within a single wave.
// ---------------------------------------------------------------------------

#define SSTMAX 1280   // per-sample floats, TYPE0 worst case (128 * 10)

__device__ __forceinline__ float fast_tanh(float x) {
    float ax = fabsf(x);
    float e  = __expf(-2.0f * ax);
    float y  = (1.0f - e) * __builtin_amdgcn_rcpf(1.0f + e);
    return copysignf(y, x);
}

template<int NA, int NB>
__device__ __forceinline__ void tanh_jet(const float (&p)[NA], const float (&q)[NB],
                                         float (&y)[NA], float (&r)[NB]) {
    constexpr int NU = ((NA - 1) > NB ? (NA - 1) : NB);
    float u[NU];
    y[0] = fast_tanh(p[0]);
    u[0] = fmaf(-y[0], y[0], 1.0f);
    if constexpr (NA >= 2) y[1] = u[0] * p[1];
    if constexpr (NU >= 2) u[1] = -2.0f * y[0] * y[1];
    if constexpr (NA >= 3) y[2] = fmaf(u[0], p[2], 0.5f * u[1] * p[1]);
    if constexpr (NU >= 3) u[2] = -fmaf(2.0f * y[0], y[2], y[1] * y[1]);
    if constexpr (NA >= 4) y[3] = fmaf(u[0], p[3], fmaf((2.0f/3.0f) * u[1], p[2],
                                       (1.0f/3.0f) * u[2] * p[1]));
    if constexpr (NU >= 4) u[3] = -2.0f * fmaf(y[0], y[3], y[1] * y[2]);
    if constexpr (NA >= 5) y[4] = fmaf(u[0], p[4], fmaf(0.75f * u[1], p[3],
                                       fmaf(0.5f * u[2], p[2], 0.25f * u[3] * p[1])));
    #pragma unroll
    for (int k = 0; k < NB; ++k) {
        float s = 0.0f;
        #pragma unroll
        for (int j = 0; j <= k; ++j) s = fmaf(u[j], q[k - j], s);
        r[k] = s;
    }
}

template<int NA, int NB, int TYPE>
__device__ __forceinline__ void eval_body(
    int bi, const float* __restrict__ inp,
    const float* __restrict__ W1, const float* __restrict__ b1,
    const float* __restrict__ W2, const float* __restrict__ b2,
    const float* __restrict__ W3, const float* __restrict__ b3,
    const float* __restrict__ W4, const float* __restrict__ b4,
    float* __restrict__ ws, int N, int NB0, float* h)
{
    constexpr int JS   = NA + NB;            // 9 / 7 / 3
    constexpr int NS4  = (JS + 1) / 4;       // float4 segments: 2 / 2 / 1
    constexpr int HAS2 = ((JS + 1) & 3) ? 1 : 0;  // trailing float2: 1 / 0 / 0
    constexpr int PEF  = 4 * NS4 + 2 * HAS2; // floats per jet entry
    constexpr int SSTf = 128 * PEF;          // per-sample float stride

    const int t  = threadIdx.x;
    const int wv = t >> 6;
    const int s  = t >> 5;                   // sample in block (0..3)
    const int g  = t & 31;
    const int i  = bi * 4 + s;
    const bool valid = (i < N);
    const int ii = valid ? i : (N - 1);

    const float a_in = inp[2 * ii + 1];
    float x_in;
    if constexpr (TYPE == 0)      x_in = inp[2 * ii + 0];
    else if constexpr (TYPE == 1) x_in = 0.0f;
    else                          x_in = 1.0f;

    float* hs = h + s * SSTf;
    float* s0f = hs;                          // float4[128]
    float* s1f = hs + 512;                    // float4[128] (if NS4==2)
    float* s2f = hs + 1024;                   // float2[128] (if HAS2)

    // ---------------- layers 1+2 fused, four K-chunks of 128 ----------------
    float acc_a[4][NA];
    float acc_b[4][NB];
    #pragma unroll
    for (int j = 0; j < 4; ++j) {
        #pragma unroll
        for (int c = 0; c < NA; ++c) acc_a[j][c] = 0.0f;
        #pragma unroll
        for (int c = 0; c < NB; ++c) acc_b[j][c] = 0.0f;
    }

    for (int ch = 0; ch < 4; ++ch) {
        // ---- layer 1: 128 neurons -> segment stores ----
        #pragma unroll
        for (int j = 0; j < 4; ++j) {
            const int kl = g + 32 * j;
            const int nn = ch * 128 + kl;
            const float wx = W1[nn];
            const float wa = W1[512 + nn];
            float d = wx + wa;
            if (d == 0.0f) d = 1e-30f;
            const float p0 = fmaf(wx, x_in, fmaf(wa, a_in, b1[nn]));
            const float y0 = fast_tanh(p0);
            const float u0 = fmaf(-y0, y0, 1.0f);
            const float e  = wx * __builtin_amdgcn_rcpf(d);
            float y1 = 0.0f, y2 = 0.0f, y3 = 0.0f, y4 = 0.0f;
            if constexpr (NA >= 2) y1 = u0 * d;
            if constexpr (NA >= 3) { const float u1 = -2.0f * y0 * y1; y2 = 0.5f * u1 * d; }
            if constexpr (NA >= 4) { const float u2 = -fmaf(2.0f * y0, y2, y1 * y1);
                                     y3 = (1.0f/3.0f) * u2 * d; }
            if constexpr (NA >= 5) { const float u3 = -2.0f * fmaf(y0, y3, y1 * y2);
                                     y4 = 0.25f * u3 * d; }
            float4 v0;
            v0.x = y0; v0.y = e * y1; v0.z = y1;
            v0.w = (NB >= 2) ? 2.0f * e * y2 : 0.0f;
            *reinterpret_cast<float4*>(s0f + 4 * kl) = v0;
            if constexpr (NS4 == 2) {
                float4 v1;
                v1.x = y2; v1.y = 3.0f * e * y3;
                v1.z = (NA >= 4) ? y3 : 0.0f;
                v1.w = (NB >= 4) ? 4.0f * e * y4 : 0.0f;
                *reinterpret_cast<float4*>(s1f + 4 * kl) = v1;
            }
            if constexpr (HAS2) {
                float2 v2; v2.x = y4; v2.y = 0.0f;
                *reinterpret_cast<float2*>(s2f + 2 * kl) = v2;
            }
        }
        __syncthreads();

        // ---- layer 2 partial: 128 k's, register-prefetch pipeline ----
        const float* Wp = W2 + ch * 16384 + 4 * g;
        float4 cv0, cv1, cw; float2 cv2;
        cv0 = *reinterpret_cast<const float4*>(s0f);
        if constexpr (NS4 == 2) cv1 = *reinterpret_cast<const float4*>(s1f);
        if constexpr (HAS2)     cv2 = *reinterpret_cast<const float2*>(s2f);
        cw = *reinterpret_cast<const float4*>(Wp);
        #pragma unroll 4
        for (int k = 0; k < 128; ++k) {
            const int kn = (k < 127) ? k + 1 : 127;
            float4 nv0, nv1, nw; float2 nv2;
            nv0 = *reinterpret_cast<const float4*>(s0f + 4 * kn);
            if constexpr (NS4 == 2) nv1 = *reinterpret_cast<const float4*>(s1f + 4 * kn);
            if constexpr (HAS2)     nv2 = *reinterpret_cast<const float2*>(s2f + 2 * kn);
            nw = *reinterpret_cast<const float4*>(Wp + 128 * kn);

            float ya[NA], za[NB];
            ya[0] = cv0.x; za[0] = cv0.y; ya[1] = cv0.z;
            if constexpr (NB >= 2) za[1] = cv0.w;
            if constexpr (NS4 == 2) {
                ya[2] = cv1.x; za[2] = cv1.y;
                if constexpr (NA >= 4) ya[3] = cv1.z;
                if constexpr (NB >= 4) za[3] = cv1.w;
            }
            if constexpr (HAS2) ya[4] = cv2.x;
            const float wa4[4] = {cw.x, cw.y, cw.z, cw.w};
            #pragma unroll
            for (int j = 0; j < 4; ++j) {
                #pragma unroll
                for (int c = 0; c < NA; ++c)
                    acc_a[j][c] = fmaf(wa4[j], ya[c], acc_a[j][c]);
                #pragma unroll
                for (int c = 0; c < NB; ++c)
                    acc_b[j][c] = fmaf(wa4[j], za[c], acc_b[j][c]);
            }
            cv0 = nv0;
            if constexpr (NS4 == 2) cv1 = nv1;
            if constexpr (HAS2)     cv2 = nv2;
            cw = nw;
        }
        __syncthreads();
    }

    // ---------------- layer-2 activation -> h2 (same segment layout) -------
    #pragma unroll
    for (int j = 0; j < 4; ++j) {
        const int n2 = 4 * g + j;
        float pj[NA], qj[NB], yj[NA], rj[NB];
        #pragma unroll
        for (int c = 0; c < NA; ++c) pj[c] = acc_a[j][c];
        pj[0] += b2[n2];
        #pragma unroll
        for (int c = 0; c < NB; ++c) qj[c] = acc_b[j][c];
        tanh_jet<NA, NB>(pj, qj, yj, rj);
        float4 v0;
        v0.x = yj[0]; v0.y = rj[0]; v0.z = (NA >= 2) ? yj[1] : 0.0f;
        v0.w = (NB >= 2) ? rj[1] : 0.0f;
        *reinterpret_cast<float4*>(s0f + 4 * n2) = v0;
        if constexpr (NS4 == 2) {
            float4 v1;
            v1.x = yj[2]; v1.y = rj[2];
            v1.z = (NA >= 4) ? yj[3] : 0.0f;
            v1.w = (NB >= 4) ? rj[3] : 0.0f;
            *reinterpret_cast<float4*>(s1f + 4 * n2) = v1;
        }
        if constexpr (HAS2) {
            float2 v2; v2.x = yj[NA - 1]; v2.y = 0.0f;
            *reinterpret_cast<float2*>(s2f + 2 * n2) = v2;
        }
    }
    __syncthreads();

    // ---------------- layer 3: 128 -> 64, register-prefetch pipeline -------
    float a3[2][NA], b3a[2][NB];
    #pragma unroll
    for (int j = 0; j < 2; ++j) {
        #pragma unroll
        for (int c = 0; c < NA; ++c) a3[j][c] = 0.0f;
        #pragma unroll
        for (int c = 0; c < NB; ++c) b3a[j][c] = 0.0f;
    }
    {
        const float* W3g = W3 + 2 * g;
        float4 cv0, cv1; float2 cv2, cw2;
        cv0 = *reinterpret_cast<const float4*>(s0f);
        if constexpr (NS4 == 2) cv1 = *reinterpret_cast<const float4*>(s1f);
        if constexpr (HAS2)     cv2 = *reinterpret_cast<const float2*>(s2f);
        cw2 = *reinterpret_cast<const float2*>(W3g);
        #pragma unroll 4
        for (int k = 0; k < 128; ++k) {
            const int kn = (k < 127) ? k + 1 : 127;
            float4 nv0, nv1; float2 nv2, nw2;
            nv0 = *reinterpret_cast<const float4*>(s0f + 4 * kn);
            if constexpr (NS4 == 2) nv1 = *reinterpret_cast<const float4*>(s1f + 4 * kn);
            if constexpr (HAS2)     nv2 = *reinterpret_cast<const float2*>(s2f + 2 * kn);
            nw2 = *reinterpret_cast<const float2*>(W3g + 64 * kn);

            float ya[NA], za[NB];
            ya[0] = cv0.x; za[0] = cv0.y; ya[1] = cv0.z;
            if constexpr (NB >= 2) za[1] = cv0.w;
            if constexpr (NS4 == 2) {
                ya[2] = cv1.x; za[2] = cv1.y;
                if constexpr (NA >= 4) ya[3] = cv1.z;
                if constexpr (NB >= 4) za[3] = cv1.w;
            }
            if constexpr (HAS2) ya[4] = cv2.x;
            #pragma unroll
            for (int c = 0; c < NA; ++c) {
                a3[0][c] = fmaf(cw2.x, ya[c], a3[0][c]);
                a3[1][c] = fmaf(cw2.y, ya[c], a3[1][c]);
            }
            #pragma unroll
            for (int c = 0; c < NB; ++c) {
                b3a[0][c] = fmaf(cw2.x, za[c], b3a[0][c]);
                b3a[1][c] = fmaf(cw2.y, za[c], b3a[1][c]);
            }
            cv0 = nv0;
            if constexpr (NS4 == 2) cv1 = nv1;
            if constexpr (HAS2)     cv2 = nv2;
            cw2 = nw2;
        }
    }

    // ---------------- layer 4 + loss ----------------
    float part[JS];
    #pragma unroll
    for (int c = 0; c < JS; ++c) part[c] = 0.0f;
    #pragma unroll
    for (int j = 0; j < 2; ++j) {
        const int n3 = 2 * g + j;
        float pj[NA], qj[NB], yj[NA], rj[NB];
        #pragma unroll
        for (int c = 0; c < NA; ++c) pj[c] = a3[j][c];
        pj[0] += b3[n3];
        #pragma unroll
        for (int c = 0; c < NB; ++c) qj[c] = b3a[j][c];
        tanh_jet<NA, NB>(pj, qj, yj, rj);
        const float w4 = W4[n3];
        #pragma unroll
        for (int c = 0; c < NA; ++c) part[c] = fmaf(w4, yj[c], part[c]);
        #pragma unroll
        for (int c = 0; c < NB; ++c) part[NA + c] = fmaf(w4, rj[c], part[NA + c]);
    }
    #pragma unroll
    for (int m = 1; m <= 16; m <<= 1)
        #pragma unroll
        for (int c = 0; c < JS; ++c)
            part[c] += __shfl_xor(part[c], m, 64);

    const float A0 = part[0] + b4[0];
    float t0 = 0.0f, t1 = 0.0f, t2 = 0.0f;
    constexpr float CC = 1.0f;   // P/(E*I)
    if constexpr (TYPE == 0) {
        const float gx = 6.0f * part[NA + 3];
        const float ga = 24.0f * part[4] - gx;
        t0 = (gx + CC) * (gx + CC) + (ga + CC) * (ga + CC);
    }
    if constexpr (TYPE == 1) {
        t0 = A0 * A0;
        const float gx = part[NA + 0];
        const float ga = part[1] - gx;
        t1 = gx * gx + ga * ga;
    }
    if constexpr (TYPE == 2) {
        const float wa = a_in * A0;
        t0 = wa * wa;
        const float g2x = part[NA + 1];
        const float g2a = 2.0f * part[2] - g2x;
        t1 = g2x * g2x + g2a * g2a;
        const float g3x = 2.0f * part[NA + 2];
        const float g3a = 6.0f * part[3] - g3x;
        const float om = 1.0f - a_in;
        t2 = om * om * (g3x * g3x + g3a * g3a);
    }
    if (!valid) { t0 = 0.0f; t1 = 0.0f; t2 = 0.0f; }

    t0 += __shfl_xor(t0, 32, 64);
    if constexpr (TYPE != 0) t1 += __shfl_xor(t1, 32, 64);
    if constexpr (TYPE == 2) t2 += __shfl_xor(t2, 32, 64);
    __syncthreads();                       // jet reads done; reuse h[0..7]
    if ((t & 63) == 0) { h[wv * 3 + 0] = t0; h[wv * 3 + 1] = t1; h[wv * 3 + 2] = t2; }
    __syncthreads();
    if (t == 0) {
        t0 = h[0] + h[3];
        t1 = h[1] + h[4];
        t2 = h[2] + h[5];
        if constexpr (TYPE == 0) {
            ws[bi] = t0;
        } else if constexpr (TYPE == 1) {
            ws[NB0 + bi]     = t0;
            ws[2 * NB0 + bi] = t1;
        } else {
            ws[3 * NB0 + bi] = t0;
            ws[4 * NB0 + bi] = t1;
            ws[5 * NB0 + bi] = t2;
        }
    }
}

__global__ __launch_bounds__(128, 4)
void pinn_fat(const float* __restrict__ inp,
              const float* __restrict__ W1, const float* __restrict__ b1,
              const float* __restrict__ W2, const float* __restrict__ b2,
              const float* __restrict__ W3, const float* __restrict__ b3,
              const float* __restrict__ W4, const float* __restrict__ b4,
              float* __restrict__ ws, int N, int NB0)
{
    __shared__ __align__(16) float h[4 * SSTMAX];   // 20480 B -> 8 blocks/CU
    const int b = blockIdx.x;
    if (b < NB0)
        eval_body<5, 4, 0>(b, inp, W1, b1, W2, b2, W3, b3, W4, b4, ws, N, NB0, h);
    else if (b < 2 * NB0)
        eval_body<4, 3, 2>(b - NB0, inp, W1, b1, W2, b2, W3, b3, W4, b4, ws, N, NB0, h);
    else
        eval_body<2, 1, 1>(b - 2 * NB0, inp, W1, b1, W2, b2, W3, b3, W4, b4, ws, N, NB0, h);
}

__global__ __launch_bounds__(1024)
void pinn_reduce(const float* __restrict__ ws, float* __restrict__ out,
                 int G, float invN, float inv2N)
{
    __shared__ float sh[16 * 6];
    float s[6];
    #pragma unroll
    for (int q = 0; q < 6; ++q) {
        float acc = 0.0f;
        for (int i = threadIdx.x; i < G; i += 1024) acc += ws[q * G + i];
        #pragma unroll
        for (int m = 1; m <= 32; m <<= 1) acc += __shfl_xor(acc, m, 64);
        s[q] = acc;
    }
    const int wid = threadIdx.x >> 6;
    if ((threadIdx.x & 63) == 0) {
        #pragma unroll
        for (int q = 0; q < 6; ++q) sh[wid * 6 + q] = s[q];
    }
    __syncthreads();
    if (threadIdx.x == 0) {
        float r[6];
        #pragma unroll
        for (int q = 0; q < 6; ++q) {
            float acc = 0.0f;
            for (int w = 0; w < 16; ++w) acc += sh[w * 6 + q];
            r[q] = acc;
        }
        const float pde   = r[0] * inv2N;
        const float w0    = r[1] * invN;
        const float w0x   = r[2] * inv2N;
        const float wL    = r[3] * invN;
        const float wLxx  = r[4] * inv2N;
        const float wLxxx = r[5] * inv2N;
        out[0] = pde + w0 + w0x + wL + wLxx + wLxxx;
        out[1] = pde;
        out[2] = w0;
        out[3] = w0x;
        out[4] = wL;
        out[5] = wLxx;
        out[6] = wLxxx;
    }
}

extern "C" void kernel_launch(void* const* d_in, const int* in_sizes, int n_in,
                              void* d_out, int out_size, void* d_ws, size_t ws_size,
                              hipStream_t stream) {
    const float* inp = (const float*)d_in[0];
    const float* W1  = (const float*)d_in[1];
    const float* b1  = (const float*)d_in[2];
    const float* W2  = (const float*)d_in[3];
    const float* b2  = (const float*)d_in[4];
    const float* W3  = (const float*)d_in[5];
    const float* b3  = (const float*)d_in[6];
    const float* W4  = (const float*)d_in[7];
    const float* b4  = (const float*)d_in[8];
    float* ws  = (float*)d_ws;
    float* out = (float*)d_out;

    const int N   = in_sizes[0] / 2;   // 32768
    const int NB0 = (N + 3) / 4;       // blocks per eval type (4 samples/block)

    pinn_fat<<<dim3(3 * NB0), dim3(128), 0, stream>>>(
        inp, W1, b1, W2, b2, W3, b3, W4, b4, ws, N, NB0);
    pinn_reduce<<<dim3(1), dim3(1024), 0, stream>>>(
        ws, out, NB0, 1.0f / (float)N, 0.5f / (float)N);
}

// Round 5
// 1438.886 us; speedup vs baseline: 1.1026x; 1.1026x over previous
//
#include <hip/hip_runtime.h>
#include <math.h>

// ---------------------------------------------------------------------------
// PINN beam loss via forward-mode bivariate jets (v5: issue-minimized).
// Jet of f(z + t*(1,1) + s*(1,0)):  y[k]=coeff t^k, z[k]=coeff t^k s.
// Layer-1: pre-act = p0 + d*t + wx*s  =>  z[k] = (k+1)*(wx/d)*y[k+1] exactly.
// LDS per sample (SoA float4 segments, 16B aligned):
//   seg0[k]=(y0,z0,y1,z1)  seg1[k]=(y2,z2,y3,z3)  seg2[k]=(y4,0)
// Inner k-loops: direct indexing, k0-tiled unroll -> LDS reads use one base
// register + immediate offsets; W loads use immediate offsets per tile.
// Steady-state VALU stream is ~pure FMA (kernel is VALU-issue-count bound).
// ---------------------------------------------------------------------------

#define SSTMAX 1280   // per-sample floats, TYPE0 worst case (128 * 10)

__device__ __forceinline__ float fast_tanh(float x) {
    float ax = fabsf(x);
    float e  = __expf(-2.0f * ax);
    float y  = (1.0f - e) * __builtin_amdgcn_rcpf(1.0f + e);
    return copysignf(y, x);
}

template<int NA, int NB>
__device__ __forceinline__ void tanh_jet(const float (&p)[NA], const float (&q)[NB],
                                         float (&y)[NA], float (&r)[NB]) {
    constexpr int NU = ((NA - 1) > NB ? (NA - 1) : NB);
    float u[NU];
    y[0] = fast_tanh(p[0]);
    u[0] = fmaf(-y[0], y[0], 1.0f);
    if constexpr (NA >= 2) y[1] = u[0] * p[1];
    if constexpr (NU >= 2) u[1] = -2.0f * y[0] * y[1];
    if constexpr (NA >= 3) y[2] = fmaf(u[0], p[2], 0.5f * u[1] * p[1]);
    if constexpr (NU >= 3) u[2] = -fmaf(2.0f * y[0], y[2], y[1] * y[1]);
    if constexpr (NA >= 4) y[3] = fmaf(u[0], p[3], fmaf((2.0f/3.0f) * u[1], p[2],
                                       (1.0f/3.0f) * u[2] * p[1]));
    if constexpr (NU >= 4) u[3] = -2.0f * fmaf(y[0], y[3], y[1] * y[2]);
    if constexpr (NA >= 5) y[4] = fmaf(u[0], p[4], fmaf(0.75f * u[1], p[3],
                                       fmaf(0.5f * u[2], p[2], 0.25f * u[3] * p[1])));
    #pragma unroll
    for (int k = 0; k < NB; ++k) {
        float s = 0.0f;
        #pragma unroll
        for (int j = 0; j <= k; ++j) s = fmaf(u[j], q[k - j], s);
        r[k] = s;
    }
}

template<int NA, int NB, int TYPE>
__device__ __forceinline__ void eval_body(
    int bi, const float* __restrict__ inp,
    const float* __restrict__ W1, const float* __restrict__ b1,
    const float* __restrict__ W2, const float* __restrict__ b2,
    const float* __restrict__ W3, const float* __restrict__ b3,
    const float* __restrict__ W4, const float* __restrict__ b4,
    float* __restrict__ ws, int N, int NB0, float* h)
{
    constexpr int JS   = NA + NB;            // 9 / 7 / 3
    constexpr int NS4  = (JS + 1) / 4;       // float4 segments: 2 / 2 / 1
    constexpr int HAS2 = ((JS + 1) & 3) ? 1 : 0;  // trailing float2: 1 / 0 / 0
    constexpr int PEF  = 4 * NS4 + 2 * HAS2; // floats per jet entry
    constexpr int SSTf = 128 * PEF;          // per-sample float stride
    constexpr int UNR  = (NS4 == 2) ? 4 : 8; // k-tile (W imm range: UNR*512B<=4KB)

    const int t  = threadIdx.x;
    const int wv = t >> 6;
    const int s  = t >> 5;                   // sample in block (0..3)
    const int g  = t & 31;
    const int i  = bi * 4 + s;
    const bool valid = (i < N);
    const int ii = valid ? i : (N - 1);

    const float a_in = inp[2 * ii + 1];
    float x_in;
    if constexpr (TYPE == 0)      x_in = inp[2 * ii + 0];
    else if constexpr (TYPE == 1) x_in = 0.0f;
    else                          x_in = 1.0f;

    float* hs  = h + s * SSTf;
    float* s0f = hs;                          // float4[128]
    float* s1f = hs + 512;                    // float4[128] (if NS4==2)
    float* s2f = hs + 1024;                   // float2[128] (if HAS2)

    // ---------------- layers 1+2 fused, four K-chunks of 128 ----------------
    float acc_a[4][NA];
    float acc_b[4][NB];
    #pragma unroll
    for (int j = 0; j < 4; ++j) {
        #pragma unroll
        for (int c = 0; c < NA; ++c) acc_a[j][c] = 0.0f;
        #pragma unroll
        for (int c = 0; c < NB; ++c) acc_b[j][c] = 0.0f;
    }

    for (int ch = 0; ch < 4; ++ch) {
        // ---- layer 1: 128 neurons -> segment stores ----
        #pragma unroll
        for (int j = 0; j < 4; ++j) {
            const int kl = g + 32 * j;
            const int nn = ch * 128 + kl;
            const float wx = W1[nn];
            const float wa = W1[512 + nn];
            float d = wx + wa;
            if (d == 0.0f) d = 1e-30f;
            const float p0 = fmaf(wx, x_in, fmaf(wa, a_in, b1[nn]));
            const float y0 = fast_tanh(p0);
            const float u0 = fmaf(-y0, y0, 1.0f);
            const float e  = wx * __builtin_amdgcn_rcpf(d);
            float y1 = 0.0f, y2 = 0.0f, y3 = 0.0f, y4 = 0.0f;
            if constexpr (NA >= 2) y1 = u0 * d;
            if constexpr (NA >= 3) { const float u1 = -2.0f * y0 * y1; y2 = 0.5f * u1 * d; }
            if constexpr (NA >= 4) { const float u2 = -fmaf(2.0f * y0, y2, y1 * y1);
                                     y3 = (1.0f/3.0f) * u2 * d; }
            if constexpr (NA >= 5) { const float u3 = -2.0f * fmaf(y0, y3, y1 * y2);
                                     y4 = 0.25f * u3 * d; }
            float4 v0;
            v0.x = y0; v0.y = e * y1; v0.z = y1;
            v0.w = (NB >= 2) ? 2.0f * e * y2 : 0.0f;
            *reinterpret_cast<float4*>(s0f + 4 * kl) = v0;
            if constexpr (NS4 == 2) {
                float4 v1;
                v1.x = y2; v1.y = 3.0f * e * y3;
                v1.z = (NA >= 4) ? y3 : 0.0f;
                v1.w = (NB >= 4) ? 4.0f * e * y4 : 0.0f;
                *reinterpret_cast<float4*>(s1f + 4 * kl) = v1;
            }
            if constexpr (HAS2) {
                float2 v2; v2.x = y4; v2.y = 0.0f;
                *reinterpret_cast<float2*>(s2f + 2 * kl) = v2;
            }
        }
        __syncthreads();

        // ---- layer 2 partial: 128 k's, pure-FMA steady state ----
        const float* __restrict__ Wp = W2 + ch * 16384 + 4 * g;
        #pragma unroll 1
        for (int k0 = 0; k0 < 128; k0 += UNR) {
            #pragma unroll
            for (int kk = 0; kk < UNR; ++kk) {
                const int k = k0 + kk;
                const float4 jv0 = *reinterpret_cast<const float4*>(s0f + 4 * k);
                float4 jv1; float2 jv2;
                if constexpr (NS4 == 2) jv1 = *reinterpret_cast<const float4*>(s1f + 4 * k);
                if constexpr (HAS2)     jv2 = *reinterpret_cast<const float2*>(s2f + 2 * k);
                const float4 wv4 = *reinterpret_cast<const float4*>(Wp + 128 * k);

                float ya[NA], za[NB];
                ya[0] = jv0.x; za[0] = jv0.y; ya[1] = jv0.z;
                if constexpr (NB >= 2) za[1] = jv0.w;
                if constexpr (NS4 == 2) {
                    ya[2] = jv1.x; za[2] = jv1.y;
                    if constexpr (NA >= 4) ya[3] = jv1.z;
                    if constexpr (NB >= 4) za[3] = jv1.w;
                }
                if constexpr (HAS2) ya[4] = jv2.x;
                const float w0 = wv4.x, w1 = wv4.y, w2 = wv4.z, w3 = wv4.w;
                #pragma unroll
                for (int c = 0; c < NA; ++c) {
                    acc_a[0][c] = fmaf(w0, ya[c], acc_a[0][c]);
                    acc_a[1][c] = fmaf(w1, ya[c], acc_a[1][c]);
                    acc_a[2][c] = fmaf(w2, ya[c], acc_a[2][c]);
                    acc_a[3][c] = fmaf(w3, ya[c], acc_a[3][c]);
                }
                #pragma unroll
                for (int c = 0; c < NB; ++c) {
                    acc_b[0][c] = fmaf(w0, za[c], acc_b[0][c]);
                    acc_b[1][c] = fmaf(w1, za[c], acc_b[1][c]);
                    acc_b[2][c] = fmaf(w2, za[c], acc_b[2][c]);
                    acc_b[3][c] = fmaf(w3, za[c], acc_b[3][c]);
                }
            }
        }
        __syncthreads();
    }

    // ---------------- layer-2 activation -> h2 (same segment layout) -------
    #pragma unroll
    for (int j = 0; j < 4; ++j) {
        const int n2 = 4 * g + j;
        float pj[NA], qj[NB], yj[NA], rj[NB];
        #pragma unroll
        for (int c = 0; c < NA; ++c) pj[c] = acc_a[j][c];
        pj[0] += b2[n2];
        #pragma unroll
        for (int c = 0; c < NB; ++c) qj[c] = acc_b[j][c];
        tanh_jet<NA, NB>(pj, qj, yj, rj);
        float4 v0;
        v0.x = yj[0]; v0.y = rj[0]; v0.z = (NA >= 2) ? yj[1] : 0.0f;
        v0.w = (NB >= 2) ? rj[1] : 0.0f;
        *reinterpret_cast<float4*>(s0f + 4 * n2) = v0;
        if constexpr (NS4 == 2) {
            float4 v1;
            v1.x = yj[2]; v1.y = rj[2];
            v1.z = (NA >= 4) ? yj[3] : 0.0f;
            v1.w = (NB >= 4) ? rj[3] : 0.0f;
            *reinterpret_cast<float4*>(s1f + 4 * n2) = v1;
        }
        if constexpr (HAS2) {
            float2 v2; v2.x = yj[NA - 1]; v2.y = 0.0f;
            *reinterpret_cast<float2*>(s2f + 2 * n2) = v2;
        }
    }
    __syncthreads();

    // ---------------- layer 3: 128 -> 64, pure-FMA steady state ------------
    float a3[2][NA], b3a[2][NB];
    #pragma unroll
    for (int j = 0; j < 2; ++j) {
        #pragma unroll
        for (int c = 0; c < NA; ++c) a3[j][c] = 0.0f;
        #pragma unroll
        for (int c = 0; c < NB; ++c) b3a[j][c] = 0.0f;
    }
    {
        const float* __restrict__ W3g = W3 + 2 * g;
        #pragma unroll 1
        for (int k0 = 0; k0 < 128; k0 += UNR) {
            #pragma unroll
            for (int kk = 0; kk < UNR; ++kk) {
                const int k = k0 + kk;
                const float4 jv0 = *reinterpret_cast<const float4*>(s0f + 4 * k);
                float4 jv1; float2 jv2;
                if constexpr (NS4 == 2) jv1 = *reinterpret_cast<const float4*>(s1f + 4 * k);
                if constexpr (HAS2)     jv2 = *reinterpret_cast<const float2*>(s2f + 2 * k);
                const float2 wv2 = *reinterpret_cast<const float2*>(W3g + 64 * k);

                float ya[NA], za[NB];
                ya[0] = jv0.x; za[0] = jv0.y; ya[1] = jv0.z;
                if constexpr (NB >= 2) za[1] = jv0.w;
                if constexpr (NS4 == 2) {
                    ya[2] = jv1.x; za[2] = jv1.y;
                    if constexpr (NA >= 4) ya[3] = jv1.z;
                    if constexpr (NB >= 4) za[3] = jv1.w;
                }
                if constexpr (HAS2) ya[4] = jv2.x;
                #pragma unroll
                for (int c = 0; c < NA; ++c) {
                    a3[0][c] = fmaf(wv2.x, ya[c], a3[0][c]);
                    a3[1][c] = fmaf(wv2.y, ya[c], a3[1][c]);
                }
                #pragma unroll
                for (int c = 0; c < NB; ++c) {
                    b3a[0][c] = fmaf(wv2.x, za[c], b3a[0][c]);
                    b3a[1][c] = fmaf(wv2.y, za[c], b3a[1][c]);
                }
            }
        }
    }

    // ---------------- layer 4 + loss ----------------
    float part[JS];
    #pragma unroll
    for (int c = 0; c < JS; ++c) part[c] = 0.0f;
    #pragma unroll
    for (int j = 0; j < 2; ++j) {
        const int n3 = 2 * g + j;
        float pj[NA], qj[NB], yj[NA], rj[NB];
        #pragma unroll
        for (int c = 0; c < NA; ++c) pj[c] = a3[j][c];
        pj[0] += b3[n3];
        #pragma unroll
        for (int c = 0; c < NB; ++c) qj[c] = b3a[j][c];
        tanh_jet<NA, NB>(pj, qj, yj, rj);
        const float w4 = W4[n3];
        #pragma unroll
        for (int c = 0; c < NA; ++c) part[c] = fmaf(w4, yj[c], part[c]);
        #pragma unroll
        for (int c = 0; c < NB; ++c) part[NA + c] = fmaf(w4, rj[c], part[NA + c]);
    }
    #pragma unroll
    for (int m = 1; m <= 16; m <<= 1)
        #pragma unroll
        for (int c = 0; c < JS; ++c)
            part[c] += __shfl_xor(part[c], m, 64);

    const float A0 = part[0] + b4[0];
    float t0 = 0.0f, t1 = 0.0f, t2 = 0.0f;
    constexpr float CC = 1.0f;   // P/(E*I)
    if constexpr (TYPE == 0) {
        const float gx = 6.0f * part[NA + 3];
        const float ga = 24.0f * part[4] - gx;
        t0 = (gx + CC) * (gx + CC) + (ga + CC) * (ga + CC);
    }
    if constexpr (TYPE == 1) {
        t0 = A0 * A0;
        const float gx = part[NA + 0];
        const float ga = part[1] - gx;
        t1 = gx * gx + ga * ga;
    }
    if constexpr (TYPE == 2) {
        const float wa = a_in * A0;
        t0 = wa * wa;
        const float g2x = part[NA + 1];
        const float g2a = 2.0f * part[2] - g2x;
        t1 = g2x * g2x + g2a * g2a;
        const float g3x = 2.0f * part[NA + 2];
        const float g3a = 6.0f * part[3] - g3x;
        const float om = 1.0f - a_in;
        t2 = om * om * (g3x * g3x + g3a * g3a);
    }
    if (!valid) { t0 = 0.0f; t1 = 0.0f; t2 = 0.0f; }

    t0 += __shfl_xor(t0, 32, 64);
    if constexpr (TYPE != 0) t1 += __shfl_xor(t1, 32, 64);
    if constexpr (TYPE == 2) t2 += __shfl_xor(t2, 32, 64);
    __syncthreads();                       // jet reads done; reuse h[0..7]
    if ((t & 63) == 0) { h[wv * 3 + 0] = t0; h[wv * 3 + 1] = t1; h[wv * 3 + 2] = t2; }
    __syncthreads();
    if (t == 0) {
        t0 = h[0] + h[3];
        t1 = h[1] + h[4];
        t2 = h[2] + h[5];
        if constexpr (TYPE == 0) {
            ws[bi] = t0;
        } else if constexpr (TYPE == 1) {
            ws[NB0 + bi]     = t0;
            ws[2 * NB0 + bi] = t1;
        } else {
            ws[3 * NB0 + bi] = t0;
            ws[4 * NB0 + bi] = t1;
            ws[5 * NB0 + bi] = t2;
        }
    }
}

__global__ __launch_bounds__(128, 4)
void pinn_fat(const float* __restrict__ inp,
              const float* __restrict__ W1, const float* __restrict__ b1,
              const float* __restrict__ W2, const float* __restrict__ b2,
              const float* __restrict__ W3, const float* __restrict__ b3,
              const float* __restrict__ W4, const float* __restrict__ b4,
              float* __restrict__ ws, int N, int NB0)
{
    __shared__ __align__(16) float h[4 * SSTMAX];   // 20480 B -> 8 blocks/CU
    const int b = blockIdx.x;
    if (b < NB0)
        eval_body<5, 4, 0>(b, inp, W1, b1, W2, b2, W3, b3, W4, b4, ws, N, NB0, h);
    else if (b < 2 * NB0)
        eval_body<4, 3, 2>(b - NB0, inp, W1, b1, W2, b2, W3, b3, W4, b4, ws, N, NB0, h);
    else
        eval_body<2, 1, 1>(b - 2 * NB0, inp, W1, b1, W2, b2, W3, b3, W4, b4, ws, N, NB0, h);
}

__global__ __launch_bounds__(1024)
void pinn_reduce(const float* __restrict__ ws, float* __restrict__ out,
                 int G, float invN, float inv2N)
{
    __shared__ float sh[16 * 6];
    float s[6];
    #pragma unroll
    for (int q = 0; q < 6; ++q) {
        float acc = 0.0f;
        for (int i = threadIdx.x; i < G; i += 1024) acc += ws[q * G + i];
        #pragma unroll
        for (int m = 1; m <= 32; m <<= 1) acc += __shfl_xor(acc, m, 64);
        s[q] = acc;
    }
    const int wid = threadIdx.x >> 6;
    if ((threadIdx.x & 63) == 0) {
        #pragma unroll
        for (int q = 0; q < 6; ++q) sh[wid * 6 + q] = s[q];
    }
    __syncthreads();
    if (threadIdx.x == 0) {
        float r[6];
        #pragma unroll
        for (int q = 0; q < 6; ++q) {
            float acc = 0.0f;
            for (int w = 0; w < 16; ++w) acc += sh[w * 6 + q];
            r[q] = acc;
        }
        const float pde   = r[0] * inv2N;
        const float w0    = r[1] * invN;
        const float w0x   = r[2] * inv2N;
        const float wL    = r[3] * invN;
        const float wLxx  = r[4] * inv2N;
        const float wLxxx = r[5] * inv2N;
        out[0] = pde + w0 + w0x + wL + wLxx + wLxxx;
        out[1] = pde;
        out[2] = w0;
        out[3] = w0x;
        out[4] = wL;
        out[5] = wLxx;
        out[6] = wLxxx;
    }
}

extern "C" void kernel_launch(void* const* d_in, const int* in_sizes, int n_in,
                              void* d_out, int out_size, void* d_ws, size_t ws_size,
                              hipStream_t stream) {
    const float* inp = (const float*)d_in[0];
    const float* W1  = (const float*)d_in[1];
    const float* b1  = (const float*)d_in[2];
    const float* W2  = (const float*)d_in[3];
    const float* b2  = (const float*)d_in[4];
    const float* W3  = (const float*)d_in[5];
    const float* b3  = (const float*)d_in[6];
    const float* W4  = (const float*)d_in[7];
    const float* b4  = (const float*)d_in[8];
    float* ws  = (float*)d_ws;
    float* out = (float*)d_out;

    const int N   = in_sizes[0] / 2;   // 32768
    const int NB0 = (N + 3) / 4;       // blocks per eval type (4 samples/block)

    pinn_fat<<<dim3(3 * NB0), dim3(128), 0, stream>>>(
        inp, W1, b1, W2, b2, W3, b3, W4, b4, ws, N, NB0);
    pinn_reduce<<<dim3(1), dim3(1024), 0, stream>>>(
        ws, out, NB0, 1.0f / (float)N, 0.5f / (float)N);
}

// Round 6
// 1210.317 us; speedup vs baseline: 1.3108x; 1.1889x over previous
//
#include <hip/hip_runtime.h>
#include <math.h>

// ---------------------------------------------------------------------------
// PINN beam loss via forward-mode bivariate jets (v6: LDS-pipe relief).
// Jet of f(z + t*(1,1) + s*(1,0)):  y[k]=coeff t^k, z[k]=coeff t^k s.
// Layer-1: pre-act = p0 + d*t + wx*s  =>  z[k] = (k+1)*(wx/d)*y[k+1] exactly.
//
// Mapping: 64-thread (1-wave) blocks, 4 samples/wave, 16 lanes/sample.
// Layer-2: 8 outputs/lane -> 72 FMA per wave-k per 3 LDS reads (2x v5 density).
// K staged in 8 chunks of 64: per-sample LDS = 648 floats (8-bank skew),
// block = 10368 B -> ~15 blocks/CU. h2 written/consumed in 2 passes of 64.
// LDS per sample (SoA float4 segments, 16B aligned):
//   seg0[k]=(y0,z0,y1,z1)  seg1[k]=(y2,z2,y3,z3)  seg2[k]=(y4,0)
// ---------------------------------------------------------------------------

#define SSTR 648   // per-sample LDS float stride (64*10 + 8 skew)

__device__ __forceinline__ float fast_tanh(float x) {
    float ax = fabsf(x);
    float e  = __expf(-2.0f * ax);
    float y  = (1.0f - e) * __builtin_amdgcn_rcpf(1.0f + e);
    return copysignf(y, x);
}

template<int NA, int NB>
__device__ __forceinline__ void tanh_jet(const float (&p)[NA], const float (&q)[NB],
                                         float (&y)[NA], float (&r)[NB]) {
    constexpr int NU = ((NA - 1) > NB ? (NA - 1) : NB);
    float u[NU];
    y[0] = fast_tanh(p[0]);
    u[0] = fmaf(-y[0], y[0], 1.0f);
    if constexpr (NA >= 2) y[1] = u[0] * p[1];
    if constexpr (NU >= 2) u[1] = -2.0f * y[0] * y[1];
    if constexpr (NA >= 3) y[2] = fmaf(u[0], p[2], 0.5f * u[1] * p[1]);
    if constexpr (NU >= 3) u[2] = -fmaf(2.0f * y[0], y[2], y[1] * y[1]);
    if constexpr (NA >= 4) y[3] = fmaf(u[0], p[3], fmaf((2.0f/3.0f) * u[1], p[2],
                                       (1.0f/3.0f) * u[2] * p[1]));
    if constexpr (NU >= 4) u[3] = -2.0f * fmaf(y[0], y[3], y[1] * y[2]);
    if constexpr (NA >= 5) y[4] = fmaf(u[0], p[4], fmaf(0.75f * u[1], p[3],
                                       fmaf(0.5f * u[2], p[2], 0.25f * u[3] * p[1])));
    #pragma unroll
    for (int k = 0; k < NB; ++k) {
        float s = 0.0f;
        #pragma unroll
        for (int j = 0; j <= k; ++j) s = fmaf(u[j], q[k - j], s);
        r[k] = s;
    }
}

template<int NA, int NB, int TYPE>
__device__ __forceinline__ void eval_body(
    int bi, const float* __restrict__ inp,
    const float* __restrict__ W1, const float* __restrict__ b1,
    const float* __restrict__ W2, const float* __restrict__ b2,
    const float* __restrict__ W3, const float* __restrict__ b3,
    const float* __restrict__ W4, const float* __restrict__ b4,
    float* __restrict__ ws, int N, int NB0, float* h)
{
    constexpr int JS   = NA + NB;            // 9 / 7 / 3
    constexpr int NS4  = (JS + 1) / 4;       // float4 segments: 2 / 2 / 1
    constexpr int HAS2 = ((JS + 1) & 3) ? 1 : 0;  // trailing float2: 1 / 0 / 0
    constexpr int UNR2 = (NS4 == 2) ? 4 : 8; // layer-2 k-tile
    constexpr int UNR3 = 8;                  // layer-3 k-tile

    const int t  = threadIdx.x;
    const int s  = t >> 4;                   // sample in wave (0..3)
    const int g  = t & 15;                   // lane within sample group
    const int i  = bi * 4 + s;
    const bool valid = (i < N);
    const int ii = valid ? i : (N - 1);

    const float a_in = inp[2 * ii + 1];
    float x_in;
    if constexpr (TYPE == 0)      x_in = inp[2 * ii + 0];
    else if constexpr (TYPE == 1) x_in = 0.0f;
    else                          x_in = 1.0f;

    float* hs  = h + s * SSTR;
    float* s0f = hs;                          // float4[64]
    float* s1f = hs + 256;                    // float4[64] (if NS4==2)
    float* s2f = hs + 512;                    // float2[64] (if HAS2)

    // ---------------- layers 1+2 fused, eight K-chunks of 64 ----------------
    float acc_a[8][NA];
    float acc_b[8][NB];
    #pragma unroll
    for (int j = 0; j < 8; ++j) {
        #pragma unroll
        for (int c = 0; c < NA; ++c) acc_a[j][c] = 0.0f;
        #pragma unroll
        for (int c = 0; c < NB; ++c) acc_b[j][c] = 0.0f;
    }

    for (int ch = 0; ch < 8; ++ch) {
        // ---- layer 1: 64 neurons/sample, 4 per lane ----
        #pragma unroll
        for (int j = 0; j < 4; ++j) {
            const int kl = g + 16 * j;
            const int nn = ch * 64 + kl;
            const float wx = W1[nn];
            const float wa = W1[512 + nn];
            float d = wx + wa;
            if (d == 0.0f) d = 1e-30f;
            const float p0 = fmaf(wx, x_in, fmaf(wa, a_in, b1[nn]));
            const float y0 = fast_tanh(p0);
            const float u0 = fmaf(-y0, y0, 1.0f);
            const float e  = wx * __builtin_amdgcn_rcpf(d);
            float y1 = 0.0f, y2 = 0.0f, y3 = 0.0f, y4 = 0.0f;
            if constexpr (NA >= 2) y1 = u0 * d;
            if constexpr (NA >= 3) { const float u1 = -2.0f * y0 * y1; y2 = 0.5f * u1 * d; }
            if constexpr (NA >= 4) { const float u2 = -fmaf(2.0f * y0, y2, y1 * y1);
                                     y3 = (1.0f/3.0f) * u2 * d; }
            if constexpr (NA >= 5) { const float u3 = -2.0f * fmaf(y0, y3, y1 * y2);
                                     y4 = 0.25f * u3 * d; }
            float4 v0;
            v0.x = y0; v0.y = e * y1; v0.z = y1;
            v0.w = (NB >= 2) ? 2.0f * e * y2 : 0.0f;
            *reinterpret_cast<float4*>(s0f + 4 * kl) = v0;
            if constexpr (NS4 == 2) {
                float4 v1;
                v1.x = y2; v1.y = 3.0f * e * y3;
                v1.z = (NA >= 4) ? y3 : 0.0f;
                v1.w = (NB >= 4) ? 4.0f * e * y4 : 0.0f;
                *reinterpret_cast<float4*>(s1f + 4 * kl) = v1;
            }
            if constexpr (HAS2) {
                float2 v2; v2.x = y4; v2.y = 0.0f;
                *reinterpret_cast<float2*>(s2f + 2 * kl) = v2;
            }
        }
        __syncthreads();

        // ---- layer 2 partial: 64 k's, 8 outputs/lane ----
        const float* __restrict__ Wp = W2 + ch * 8192 + 8 * g;
        #pragma unroll 1
        for (int k0 = 0; k0 < 64; k0 += UNR2) {
            #pragma unroll
            for (int kk = 0; kk < UNR2; ++kk) {
                const int k = k0 + kk;
                const float4 jv0 = *reinterpret_cast<const float4*>(s0f + 4 * k);
                float4 jv1; float2 jv2;
                if constexpr (NS4 == 2) jv1 = *reinterpret_cast<const float4*>(s1f + 4 * k);
                if constexpr (HAS2)     jv2 = *reinterpret_cast<const float2*>(s2f + 2 * k);
                const float4 wva = *reinterpret_cast<const float4*>(Wp + 128 * k);
                const float4 wvb = *reinterpret_cast<const float4*>(Wp + 128 * k + 4);

                float ya[NA], za[NB];
                ya[0] = jv0.x; za[0] = jv0.y; ya[1] = jv0.z;
                if constexpr (NB >= 2) za[1] = jv0.w;
                if constexpr (NS4 == 2) {
                    ya[2] = jv1.x; za[2] = jv1.y;
                    if constexpr (NA >= 4) ya[3] = jv1.z;
                    if constexpr (NB >= 4) za[3] = jv1.w;
                }
                if constexpr (HAS2) ya[4] = jv2.x;
                const float w[8] = {wva.x, wva.y, wva.z, wva.w,
                                    wvb.x, wvb.y, wvb.z, wvb.w};
                #pragma unroll
                for (int j = 0; j < 8; ++j) {
                    #pragma unroll
                    for (int c = 0; c < NA; ++c)
                        acc_a[j][c] = fmaf(w[j], ya[c], acc_a[j][c]);
                    #pragma unroll
                    for (int c = 0; c < NB; ++c)
                        acc_b[j][c] = fmaf(w[j], za[c], acc_b[j][c]);
                }
            }
        }
        __syncthreads();
    }

    // ---------------- layer-2 activation (in registers, 8 n2/lane) ---------
    #pragma unroll
    for (int j = 0; j < 8; ++j) {
        const int n2 = 8 * g + j;
        float pj[NA], qj[NB], yj[NA], rj[NB];
        #pragma unroll
        for (int c = 0; c < NA; ++c) pj[c] = acc_a[j][c];
        pj[0] += b2[n2];
        #pragma unroll
        for (int c = 0; c < NB; ++c) qj[c] = acc_b[j][c];
        tanh_jet<NA, NB>(pj, qj, yj, rj);
        #pragma unroll
        for (int c = 0; c < NA; ++c) acc_a[j][c] = yj[c];
        #pragma unroll
        for (int c = 0; c < NB; ++c) acc_b[j][c] = rj[c];
    }

    // ---------------- layer 3: 128 -> 64 in two 64-entry passes ------------
    float a3[4][NA], b3c[4][NB];
    #pragma unroll
    for (int j = 0; j < 4; ++j) {
        #pragma unroll
        for (int c = 0; c < NA; ++c) a3[j][c] = 0.0f;
        #pragma unroll
        for (int c = 0; c < NB; ++c) b3c[j][c] = 0.0f;
    }
    #pragma unroll 1
    for (int pass = 0; pass < 2; ++pass) {
        __syncthreads();                     // previous buffer reads done
        if ((g >> 3) == pass) {              // 8 lanes own n2 in this half
            const int gh = g & 7;
            #pragma unroll
            for (int j = 0; j < 8; ++j) {
                const int idx = 8 * gh + j;  // 0..63
                float4 v0;
                v0.x = acc_a[j][0]; v0.y = acc_b[j][0];
                v0.z = (NA >= 2) ? acc_a[j][1] : 0.0f;
                v0.w = (NB >= 2) ? acc_b[j][1] : 0.0f;
                *reinterpret_cast<float4*>(s0f + 4 * idx) = v0;
                if constexpr (NS4 == 2) {
                    float4 v1;
                    v1.x = acc_a[j][2]; v1.y = acc_b[j][2];
                    v1.z = (NA >= 4) ? acc_a[j][3] : 0.0f;
                    v1.w = (NB >= 4) ? acc_b[j][3] : 0.0f;
                    *reinterpret_cast<float4*>(s1f + 4 * idx) = v1;
                }
                if constexpr (HAS2) {
                    float2 v2; v2.x = acc_a[j][NA - 1]; v2.y = 0.0f;
                    *reinterpret_cast<float2*>(s2f + 2 * idx) = v2;
                }
            }
        }
        __syncthreads();

        const float* __restrict__ W3g = W3 + pass * 4096 + 4 * g;
        #pragma unroll 1
        for (int k0 = 0; k0 < 64; k0 += UNR3) {
            #pragma unroll
            for (int kk = 0; kk < UNR3; ++kk) {
                const int k = k0 + kk;
                const float4 jv0 = *reinterpret_cast<const float4*>(s0f + 4 * k);
                float4 jv1; float2 jv2;
                if constexpr (NS4 == 2) jv1 = *reinterpret_cast<const float4*>(s1f + 4 * k);
                if constexpr (HAS2)     jv2 = *reinterpret_cast<const float2*>(s2f + 2 * k);
                const float4 wv4 = *reinterpret_cast<const float4*>(W3g + 64 * k);

                float ya[NA], za[NB];
                ya[0] = jv0.x; za[0] = jv0.y; ya[1] = jv0.z;
                if constexpr (NB >= 2) za[1] = jv0.w;
                if constexpr (NS4 == 2) {
                    ya[2] = jv1.x; za[2] = jv1.y;
                    if constexpr (NA >= 4) ya[3] = jv1.z;
                    if constexpr (NB >= 4) za[3] = jv1.w;
                }
                if constexpr (HAS2) ya[4] = jv2.x;
                const float w[4] = {wv4.x, wv4.y, wv4.z, wv4.w};
                #pragma unroll
                for (int j = 0; j < 4; ++j) {
                    #pragma unroll
                    for (int c = 0; c < NA; ++c)
                        a3[j][c] = fmaf(w[j], ya[c], a3[j][c]);
                    #pragma unroll
                    for (int c = 0; c < NB; ++c)
                        b3c[j][c] = fmaf(w[j], za[c], b3c[j][c]);
                }
            }
        }
    }

    // ---------------- layer 4 + loss (4 n3/lane) ----------------
    float part[JS];
    #pragma unroll
    for (int c = 0; c < JS; ++c) part[c] = 0.0f;
    const float4 b3v = *reinterpret_cast<const float4*>(b3 + 4 * g);
    const float4 w4v = *reinterpret_cast<const float4*>(W4 + 4 * g);
    const float b3a4[4] = {b3v.x, b3v.y, b3v.z, b3v.w};
    const float w4a4[4] = {w4v.x, w4v.y, w4v.z, w4v.w};
    #pragma unroll
    for (int j = 0; j < 4; ++j) {
        float pj[NA], qj[NB], yj[NA], rj[NB];
        #pragma unroll
        for (int c = 0; c < NA; ++c) pj[c] = a3[j][c];
        pj[0] += b3a4[j];
        #pragma unroll
        for (int c = 0; c < NB; ++c) qj[c] = b3c[j][c];
        tanh_jet<NA, NB>(pj, qj, yj, rj);
        #pragma unroll
        for (int c = 0; c < NA; ++c) part[c] = fmaf(w4a4[j], yj[c], part[c]);
        #pragma unroll
        for (int c = 0; c < NB; ++c) part[NA + c] = fmaf(w4a4[j], rj[c], part[NA + c]);
    }
    #pragma unroll
    for (int m = 1; m <= 8; m <<= 1)
        #pragma unroll
        for (int c = 0; c < JS; ++c)
            part[c] += __shfl_xor(part[c], m, 64);
    // all 16 lanes of each group now hold their sample's output jet

    const float A0 = part[0] + b4[0];
    float t0 = 0.0f, t1 = 0.0f, t2 = 0.0f;
    constexpr float CC = 1.0f;   // P/(E*I)
    if constexpr (TYPE == 0) {
        const float gx = 6.0f * part[NA + 3];
        const float ga = 24.0f * part[4] - gx;
        t0 = (gx + CC) * (gx + CC) + (ga + CC) * (ga + CC);
    }
    if constexpr (TYPE == 1) {
        t0 = A0 * A0;
        const float gx = part[NA + 0];
        const float ga = part[1] - gx;
        t1 = gx * gx + ga * ga;
    }
    if constexpr (TYPE == 2) {
        const float wa = a_in * A0;
        t0 = wa * wa;
        const float g2x = part[NA + 1];
        const float g2a = 2.0f * part[2] - g2x;
        t1 = g2x * g2x + g2a * g2a;
        const float g3x = 2.0f * part[NA + 2];
        const float g3a = 6.0f * part[3] - g3x;
        const float om = 1.0f - a_in;
        t2 = om * om * (g3x * g3x + g3a * g3a);
    }
    if (!valid) { t0 = 0.0f; t1 = 0.0f; t2 = 0.0f; }

    // sum the wave's 4 samples (cross-group butterflies)
    t0 += __shfl_xor(t0, 16, 64); t0 += __shfl_xor(t0, 32, 64);
    if constexpr (TYPE != 0) { t1 += __shfl_xor(t1, 16, 64); t1 += __shfl_xor(t1, 32, 64); }
    if constexpr (TYPE == 2) { t2 += __shfl_xor(t2, 16, 64); t2 += __shfl_xor(t2, 32, 64); }

    if (t == 0) {
        if constexpr (TYPE == 0) {
            ws[bi] = t0;
        } else if constexpr (TYPE == 1) {
            ws[NB0 + bi]     = t0;
            ws[2 * NB0 + bi] = t1;
        } else {
            ws[3 * NB0 + bi] = t0;
            ws[4 * NB0 + bi] = t1;
            ws[5 * NB0 + bi] = t2;
        }
    }
}

__global__ __launch_bounds__(64, 3)
void pinn_fat(const float* __restrict__ inp,
              const float* __restrict__ W1, const float* __restrict__ b1,
              const float* __restrict__ W2, const float* __restrict__ b2,
              const float* __restrict__ W3, const float* __restrict__ b3,
              const float* __restrict__ W4, const float* __restrict__ b4,
              float* __restrict__ ws, int N, int NB0)
{
    __shared__ __align__(16) float h[4 * SSTR];    // 10368 B -> ~15 blocks/CU
    const int b = blockIdx.x;
    if (b < NB0)
        eval_body<5, 4, 0>(b, inp, W1, b1, W2, b2, W3, b3, W4, b4, ws, N, NB0, h);
    else if (b < 2 * NB0)
        eval_body<4, 3, 2>(b - NB0, inp, W1, b1, W2, b2, W3, b3, W4, b4, ws, N, NB0, h);
    else
        eval_body<2, 1, 1>(b - 2 * NB0, inp, W1, b1, W2, b2, W3, b3, W4, b4, ws, N, NB0, h);
}

__global__ __launch_bounds__(1024)
void pinn_reduce(const float* __restrict__ ws, float* __restrict__ out,
                 int G, float invN, float inv2N)
{
    __shared__ float sh[16 * 6];
    float s[6];
    #pragma unroll
    for (int q = 0; q < 6; ++q) {
        float acc = 0.0f;
        for (int i = threadIdx.x; i < G; i += 1024) acc += ws[q * G + i];
        #pragma unroll
        for (int m = 1; m <= 32; m <<= 1) acc += __shfl_xor(acc, m, 64);
        s[q] = acc;
    }
    const int wid = threadIdx.x >> 6;
    if ((threadIdx.x & 63) == 0) {
        #pragma unroll
        for (int q = 0; q < 6; ++q) sh[wid * 6 + q] = s[q];
    }
    __syncthreads();
    if (threadIdx.x == 0) {
        float r[6];
        #pragma unroll
        for (int q = 0; q < 6; ++q) {
            float acc = 0.0f;
            for (int w = 0; w < 16; ++w) acc += sh[w * 6 + q];
            r[q] = acc;
        }
        const float pde   = r[0] * inv2N;
        const float w0    = r[1] * invN;
        const float w0x   = r[2] * inv2N;
        const float wL    = r[3] * invN;
        const float wLxx  = r[4] * inv2N;
        const float wLxxx = r[5] * inv2N;
        out[0] = pde + w0 + w0x + wL + wLxx + wLxxx;
        out[1] = pde;
        out[2] = w0;
        out[3] = w0x;
        out[4] = wL;
        out[5] = wLxx;
        out[6] = wLxxx;
    }
}

extern "C" void kernel_launch(void* const* d_in, const int* in_sizes, int n_in,
                              void* d_out, int out_size, void* d_ws, size_t ws_size,
                              hipStream_t stream) {
    const float* inp = (const float*)d_in[0];
    const float* W1  = (const float*)d_in[1];
    const float* b1  = (const float*)d_in[2];
    const float* W2  = (const float*)d_in[3];
    const float* b2  = (const float*)d_in[4];
    const float* W3  = (const float*)d_in[5];
    const float* b3  = (const float*)d_in[6];
    const float* W4  = (const float*)d_in[7];
    const float* b4  = (const float*)d_in[8];
    float* ws  = (float*)d_ws;
    float* out = (float*)d_out;

    const int N   = in_sizes[0] / 2;   // 32768
    const int NB0 = (N + 3) / 4;       // blocks per eval type (4 samples/block)

    pinn_fat<<<dim3(3 * NB0), dim3(64), 0, stream>>>(
        inp, W1, b1, W2, b2, W3, b3, W4, b4, ws, N, NB0);
    pinn_reduce<<<dim3(1), dim3(1024), 0, stream>>>(
        ws, out, NB0, 1.0f / (float)N, 0.5f / (float)N);
}